// Round 9
// baseline (47008.051 us; speedup 1.0000x reference)
//
#include <hip/hip_runtime.h>

// R9 = R8 retry: R8's bench died with a harness-level ExceptionGroup (Trio
// nursery) -- no compile error, no absmax, no test output. The raw-barrier
// idiom below is the standard CK pattern and cannot deadlock (uniform
// control flow, full vmcnt queue stalls issue rather than hanging).
// Resubmitting to get the experiment's data point.

#define S_LEN 65536
#define HDIM 128

typedef _Float16 half2_t __attribute__((ext_vector_type(2)));
typedef _Float16 half8_t __attribute__((ext_vector_type(8)));
typedef float f32x4 __attribute__((ext_vector_type(4)));

__device__ __forceinline__ float sigm(float x) {
    return 1.0f / (1.0f + __expf(-x));
}
__device__ __forceinline__ float tanh_fast(float x) {
    return 2.0f / (1.0f + __expf(-2.0f * x)) - 1.0f;
}
__device__ __forceinline__ float dot2(half2_t a, half2_t b, float c) {
#if __has_builtin(__builtin_amdgcn_fdot2)
    return __builtin_amdgcn_fdot2(a, b, c, false);
#else
    return fmaf((float)a.x, (float)b.x, fmaf((float)a.y, (float)b.y, c));
#endif
}

// Raw workgroup barrier WITHOUT the vmcnt(0) drain __syncthreads() emits.
// LDS producer->consumer across waves needs only lgkmcnt(0) + rendezvous.
// Global ops in flight (h_hist store, x prefetch) are NOT consumed by other
// waves in this kernel -- inter-kernel visibility comes from dispatch
// ordering -- so letting them float past the barrier is safe.
__device__ __forceinline__ void block_sync_lds() {
    asm volatile("s_waitcnt lgkmcnt(0)" ::: "memory");
    __builtin_amdgcn_s_barrier();
}

// ================= Kernel 1: MFMA recurrence =================
__global__ __launch_bounds__(512)
__attribute__((amdgpu_waves_per_eu(2, 2)))
void lstm_seq_mfma(const float* __restrict__ x,
                   const float* __restrict__ h0,
                   const float* __restrict__ c0,
                   const float* __restrict__ W_ih,
                   const float* __restrict__ W_hh,
                   const float* __restrict__ b_ih,
                   const float* __restrict__ b_hh,
                   _Float16* __restrict__ h_hist)
{
    __shared__ __align__(16) _Float16 h_sh16[HDIM];   // h_t, packed f16
    __shared__ __align__(16) float gates_sh[4 * HDIM];

    const int tid  = threadIdx.x;       // 0..511, 8 waves
    const int lane = tid & 63;
    const int w    = tid >> 6;          // wave id 0..7: rows [w*64, w*64+64)
    const int m    = lane & 15;         // A-fragment row within tile
    const int quad = lane >> 4;         // 0..3

    // ---- A fragments: 4 row-tiles x 4 k-chunks, f32->f16, asm-pinned ----
#define LOAD_AF(i, q) \
    half8_t af_##i##_##q; { \
        const float* s_ = W_hh + (size_t)(w * 64 + 16 * (i) + m) * HDIM \
                               + 32 * (q) + 8 * quad; \
        af_##i##_##q = (half8_t){ \
            (_Float16)s_[0], (_Float16)s_[1], (_Float16)s_[2], (_Float16)s_[3], \
            (_Float16)s_[4], (_Float16)s_[5], (_Float16)s_[6], (_Float16)s_[7] }; \
        asm volatile("" : "+v"(af_##i##_##q)); }
    LOAD_AF(0, 0) LOAD_AF(0, 1) LOAD_AF(0, 2) LOAD_AF(0, 3)
    LOAD_AF(1, 0) LOAD_AF(1, 1) LOAD_AF(1, 2) LOAD_AF(1, 3)
    LOAD_AF(2, 0) LOAD_AF(2, 1) LOAD_AF(2, 2) LOAD_AF(2, 3)
    LOAD_AF(3, 0) LOAD_AF(3, 1) LOAD_AF(3, 2) LOAD_AF(3, 3)
#undef LOAD_AF

    // ---- Phase-B per-thread state (waves 0,1 only): x-proj + bias + c ----
    float wi0x = 0.f, wi0y = 0.f, bs0 = 0.f;
    float wi1x = 0.f, wi1y = 0.f, bs1 = 0.f;
    float wi2x = 0.f, wi2y = 0.f, bs2 = 0.f;
    float wi3x = 0.f, wi3y = 0.f, bs3 = 0.f;
    float c = 0.0f;
    if (tid < HDIM) {
        wi0x = W_ih[2 * tid];            wi0y = W_ih[2 * tid + 1];
        wi1x = W_ih[2 * (tid + 128)];    wi1y = W_ih[2 * (tid + 128) + 1];
        wi2x = W_ih[2 * (tid + 256)];    wi2y = W_ih[2 * (tid + 256) + 1];
        wi3x = W_ih[2 * (tid + 384)];    wi3y = W_ih[2 * (tid + 384) + 1];
        bs0 = b_ih[tid]       + b_hh[tid];
        bs1 = b_ih[tid + 128] + b_hh[tid + 128];
        bs2 = b_ih[tid + 256] + b_hh[tid + 256];
        bs3 = b_ih[tid + 384] + b_hh[tid + 384];
        c = c0[tid];
        h_sh16[tid] = (_Float16)h0[tid];
    }
    __syncthreads();   // once, pre-loop: full drain is fine here

    const float2* xp = (const float2*)x;
    float2 xcur = {0.f, 0.f}, xnext = {0.f, 0.f};
    if (tid < HDIM) xcur = xp[0];

    half8_t bf0 = (half8_t){0,0,0,0,0,0,0,0};
    half8_t bf1 = bf0, bf2 = bf0, bf3 = bf0;

    #pragma unroll 1
    for (int t = 0; t < S_LEN; ++t) {
        // ---- Phase A: gates = W_hh . h via MFMA ----
        if (m == 0) {  // lanes 0,16,32,48: load B-fragment (col 0 = h)
            const half8_t* hb = (const half8_t*)h_sh16;  // 16 chunks of 8 f16
            bf0 = hb[quad];        // k = 8*quad + j
            bf1 = hb[4 + quad];    // k = 32 + 8*quad + j
            bf2 = hb[8 + quad];    // k = 64 + 8*quad + j
            bf3 = hb[12 + quad];   // k = 96 + 8*quad + j
        }
        f32x4 acc0 = {0.f, 0.f, 0.f, 0.f};
        f32x4 acc1 = {0.f, 0.f, 0.f, 0.f};
        f32x4 acc2 = {0.f, 0.f, 0.f, 0.f};
        f32x4 acc3 = {0.f, 0.f, 0.f, 0.f};
#define MFMA_TILE(i) \
        acc##i = __builtin_amdgcn_mfma_f32_16x16x32_f16(af_##i##_0, bf0, acc##i, 0, 0, 0); \
        acc##i = __builtin_amdgcn_mfma_f32_16x16x32_f16(af_##i##_1, bf1, acc##i, 0, 0, 0); \
        acc##i = __builtin_amdgcn_mfma_f32_16x16x32_f16(af_##i##_2, bf2, acc##i, 0, 0, 0); \
        acc##i = __builtin_amdgcn_mfma_f32_16x16x32_f16(af_##i##_3, bf3, acc##i, 0, 0, 0);
        MFMA_TILE(0) MFMA_TILE(1) MFMA_TILE(2) MFMA_TILE(3)
#undef MFMA_TILE
        if (m == 0) {  // col-0 lanes hold gates: reg r = row 16*i + 4*quad + r
            f32x4* gp = (f32x4*)gates_sh + w * 16 + quad;
            gp[0]  = acc0;   // tile 0: rows w*64 + 4*quad + {0..3}
            gp[4]  = acc1;   // tile 1: +16
            gp[8]  = acc2;   // tile 2: +32
            gp[12] = acc3;   // tile 3: +48
        }

        if (tid < HDIM) {
            const int tn = (t + 1 < S_LEN) ? (t + 1) : (S_LEN - 1);
            xnext = xp[tn];   // prefetch next x (waves 0-1 only)
        }
        block_sync_lds();  // barrier 1: gates visible (lgkmcnt only)

        // ---- Phase B: activations + state update (waves 0,1) ----
        if (tid < HDIM) {
            float gi = sigm(gates_sh[tid]
                            + fmaf(wi0x, xcur.x, fmaf(wi0y, xcur.y, bs0)));
            float gf = sigm(gates_sh[tid + 128]
                            + fmaf(wi1x, xcur.x, fmaf(wi1y, xcur.y, bs1)));
            float gg = tanh_fast(gates_sh[tid + 256]
                            + fmaf(wi2x, xcur.x, fmaf(wi2y, xcur.y, bs2)));
            float go = sigm(gates_sh[tid + 384]
                            + fmaf(wi3x, xcur.x, fmaf(wi3y, xcur.y, bs3)));
            c = fmaf(gf, c, gi * gg);
            float h = go * tanh_fast(c);
            _Float16 hf = (_Float16)h;
            h_sh16[tid] = hf;                  // feeds next step's B-frags
            h_hist[t * HDIM + tid] = hf;       // floats past the barrier
            xcur = xnext;
        }
        block_sync_lds();  // barrier 2: h_t visible (no store-ack stall)
    }
}

// ================= Kernel 2: out[t] = tanh(h_t).W_out + b =================
__global__ __launch_bounds__(256)
void out_proj(const _Float16* __restrict__ h_hist,
              const float* __restrict__ W_out,
              const float* __restrict__ b_out,
              float* __restrict__ out)
{
    const int lane  = threadIdx.x & 63;
    const int gwave = (blockIdx.x * 256 + threadIdx.x) >> 6;
    const int nwave = (gridDim.x * 256) >> 6;

    const float wo0 = W_out[2 * lane + 0];
    const float wo1 = W_out[2 * lane + 1];
    const float bout = b_out[0];

    for (int t = gwave; t < S_LEN; t += nwave) {
        half2_t hv = ((const half2_t*)(h_hist + t * HDIM))[lane];
        float p = tanh_fast((float)hv.x) * wo0 + tanh_fast((float)hv.y) * wo1;
        #pragma unroll
        for (int off = 32; off > 0; off >>= 1)
            p += __shfl_xor(p, off, 64);
        if (lane == 0) out[t] = p + bout;
    }
}

// ================= Fallback: fused single kernel (ws too small) ===========
#define H_HI_OFF 144
__global__ __launch_bounds__(1024)
__attribute__((amdgpu_waves_per_eu(4, 4)))
void lstm_seq_full(const float* __restrict__ x,
                   const float* __restrict__ h0,
                   const float* __restrict__ c0,
                   const float* __restrict__ W_ih,
                   const float* __restrict__ W_hh,
                   const float* __restrict__ b_ih,
                   const float* __restrict__ b_hh,
                   const float* __restrict__ W_out,
                   const float* __restrict__ b_out,
                   float* __restrict__ out)
{
    __shared__ __align__(16) unsigned char h_raw[2 * H_HI_OFF];
    __shared__ float gates_part[2 * 512];
    __shared__ float red_sh[2];

    const int tid  = threadIdx.x;
    const int j    = tid >> 1;
    const int half = tid & 1;

    const float2* wr2 = (const float2*)(W_hh + j * HDIM + half * 64);
#define WDEF(i) half2_t W##i; { float2 t = wr2[i]; \
        W##i.x = (_Float16)t.x; W##i.y = (_Float16)t.y; } \
        asm volatile("" : "+v"(W##i));
    WDEF(0)  WDEF(1)  WDEF(2)  WDEF(3)  WDEF(4)  WDEF(5)  WDEF(6)  WDEF(7)
    WDEF(8)  WDEF(9)  WDEF(10) WDEF(11) WDEF(12) WDEF(13) WDEF(14) WDEF(15)
    WDEF(16) WDEF(17) WDEF(18) WDEF(19) WDEF(20) WDEF(21) WDEF(22) WDEF(23)
    WDEF(24) WDEF(25) WDEF(26) WDEF(27) WDEF(28) WDEF(29) WDEF(30) WDEF(31)
#undef WDEF

    float wih0 = 0.0f, wih1 = 0.0f, bias = 0.0f;
    if (half == 0) {
        wih0 = W_ih[2 * j + 0];
        wih1 = W_ih[2 * j + 1];
        bias = b_ih[j] + b_hh[j];
    }

    float c = 0.0f, wout = 0.0f;
    _Float16* hw = (_Float16*)(h_raw + ((tid < 64) ? 2 * tid
                                                   : H_HI_OFF + 2 * (tid - 64)));
    if (tid < HDIM) {
        c = c0[tid];
        wout = W_out[tid];
        *hw = (_Float16)h0[tid];
    }
    const float bout = b_out[0];
    __syncthreads();

    const float2* xp = (const float2*)x;
    float2 xcur = xp[0];
    const half8_t* hp = (const half8_t*)(h_raw + half * H_HI_OFF);

    #pragma unroll 1
    for (int t = 0; t < S_LEN; ++t) {
        const int tn = (t + 1 < S_LEN) ? (t + 1) : (S_LEN - 1);
        float2 xnext = xp[tn];

        float a0 = fmaf(wih0, xcur.x, fmaf(wih1, xcur.y, bias));
        float a1 = 0.0f, a2 = 0.0f, a3 = 0.0f;

#define CHUNK(cc, w0_, w1_, w2_, w3_) {                         \
        half8_t hv = hp[cc];                                    \
        half2_t p0 = { hv[0], hv[1] };                          \
        half2_t p1 = { hv[2], hv[3] };                          \
        half2_t p2 = { hv[4], hv[5] };                          \
        half2_t p3 = { hv[6], hv[7] };                          \
        a0 = dot2(w0_, p0, a0);                                 \
        a1 = dot2(w1_, p1, a1);                                 \
        a2 = dot2(w2_, p2, a2);                                 \
        a3 = dot2(w3_, p3, a3); }
        CHUNK(0, W0,  W1,  W2,  W3)
        CHUNK(1, W4,  W5,  W6,  W7)
        CHUNK(2, W8,  W9,  W10, W11)
        CHUNK(3, W12, W13, W14, W15)
        CHUNK(4, W16, W17, W18, W19)
        CHUNK(5, W20, W21, W22, W23)
        CHUNK(6, W24, W25, W26, W27)
        CHUNK(7, W28, W29, W30, W31)
#undef CHUNK

        gates_part[half * 512 + j] = (a0 + a1) + (a2 + a3);
        __syncthreads();

        if (tid < HDIM) {
            float gi = sigm(gates_part[tid]            + gates_part[tid + 512]);
            float gf = sigm(gates_part[tid + 128]      + gates_part[tid + 640]);
            float gg = tanh_fast(gates_part[tid + 256] + gates_part[tid + 768]);
            float go = sigm(gates_part[tid + 384]      + gates_part[tid + 896]);
            c = fmaf(gf, c, gi * gg);
            float h = go * tanh_fast(c);
            *hw = (_Float16)h;

            float p = tanh_fast(h) * wout;
            #pragma unroll
            for (int off = 32; off > 0; off >>= 1)
                p += __shfl_xor(p, off, 64);
            if ((tid & 63) == 0) red_sh[tid >> 6] = p;
        }
        __syncthreads();

        if (tid == 0) out[t] = red_sh[0] + red_sh[1] + bout;
        xcur = xnext;
    }
}

extern "C" void kernel_launch(void* const* d_in, const int* in_sizes, int n_in,
                              void* d_out, int out_size, void* d_ws, size_t ws_size,
                              hipStream_t stream) {
    const float* x     = (const float*)d_in[0];
    const float* h0    = (const float*)d_in[1];
    const float* c0    = (const float*)d_in[2];
    const float* W_ih  = (const float*)d_in[3];
    const float* W_hh  = (const float*)d_in[4];
    const float* b_ih  = (const float*)d_in[5];
    const float* b_hh  = (const float*)d_in[6];
    const float* W_out = (const float*)d_in[7];
    const float* b_out = (const float*)d_in[8];

    const size_t need = (size_t)S_LEN * HDIM * sizeof(_Float16);  // 16 MiB
    if (ws_size >= need) {
        _Float16* h_hist = (_Float16*)d_ws;
        lstm_seq_mfma<<<dim3(1), dim3(512), 0, stream>>>(
            x, h0, c0, W_ih, W_hh, b_ih, b_hh, h_hist);
        out_proj<<<dim3(1024), dim3(256), 0, stream>>>(
            h_hist, W_out, b_out, (float*)d_out);
    } else {
        lstm_seq_full<<<dim3(1), dim3(1024), 0, stream>>>(
            x, h0, c0, W_ih, W_hh, b_ih, b_hh, W_out, b_out, (float*)d_out);
    }
}